// Round 10
// baseline (370.902 us; speedup 1.0000x reference)
//
#include <hip/hip_runtime.h>

#define SLOTCAP 64

typedef __attribute__((ext_vector_type(8))) short bf16x8;
typedef __attribute__((ext_vector_type(4))) float f32x4;
typedef unsigned short u16;
typedef unsigned int   u32;

__device__ inline u16 f2bf(float f) {
    u32 u = __float_as_uint(f);
    u32 r = (u + 0x7fffu + ((u >> 16) & 1u)) >> 16;   // RNE
    return (u16)r;
}
__device__ inline float bf2f(u16 h) { return __uint_as_float(((u32)h) << 16); }
__device__ inline u32 packhl(float f) {               // hi | lo<<16
    u16 h = f2bf(f);
    u16 l = f2bf(f - bf2f(h));
    return (u32)h | ((u32)l << 16);
}
__device__ inline float unpackhl(u32 u) {
    return bf2f((u16)u) + bf2f((u16)(u >> 16));
}

// ---------- adjacency build: bucket edges by target ----------
__global__ void k_fill(const int* __restrict__ rowv, const int* __restrict__ colv,
                       int* __restrict__ fill, int* __restrict__ slots, int E) {
    int e = blockIdx.x * blockDim.x + threadIdx.x;
    if (e >= E) return;
    int c = colv[e];
    int pos = atomicAdd(&fill[c], 1);
    if (pos < SLOTCAP) slots[c * SLOTCAP + pos] = rowv[e];
}

// ---------- per-slot weights ----------
__global__ void k_wfill(const int* __restrict__ fill, const int* __restrict__ slots,
                        const float* __restrict__ dinv, float* __restrict__ wbuf, int N) {
    int i = blockIdx.x * 256 + threadIdx.x;
    if (i >= N * SLOTCAP) return;
    const int node = i >> 6, sl = i & 63;
    const int deg = min(fill[node], SLOTCAP);
    wbuf[i] = (sl < deg) ? dinv[slots[i]] : 0.0f;
}

// ---------- f32 -> packed hi|lo u32 per dim (+ dinv) ----------
__global__ void k_split_x(const float* __restrict__ x, u32* __restrict__ X,
                          const int* __restrict__ fill, float* __restrict__ dinv,
                          int Nreal, int Mpad) {
    int idx = blockIdx.x * 256 + threadIdx.x;      // one thread per 4 dims
    int total = Mpad * 32;
    if (idx >= total) return;
    const int row = idx >> 5, c4 = (idx & 31) * 4;
    if (c4 == 0 && row < Nreal)
        dinv[row] = (float)(1.0 / sqrt((double)(fill[row] + 1)));   // +1 self-loop
    float4 v = make_float4(0.f, 0.f, 0.f, 0.f);
    if (row < Nreal) v = *(const float4*)(x + (size_t)row * 128 + c4);
    uint4 o;
    o.x = packhl(v.x); o.y = packhl(v.y); o.z = packhl(v.z); o.w = packhl(v.w);
    *(uint4*)(X + (size_t)row * 128 + c4) = o;
}

// ---------- weights -> planar bf16 hi|lo slabs [128][256] ----------
__global__ void k_split_w(const float* __restrict__ W0, const float* __restrict__ W1,
                          const float* __restrict__ W2, const float* __restrict__ W3,
                          u16* __restrict__ Wcat) {
    const int l = blockIdx.y;
    const float* W = (l == 0) ? W0 : (l == 1) ? W1 : (l == 2) ? W2 : W3;
    const int rows = (l == 3) ? 64 : 128;
    int idx = blockIdx.x * 256 + threadIdx.x;
    if (idx >= rows * 128) return;
    const int r = idx >> 7, c = idx & 127;
    float v = W[idx];
    u16 h = f2bf(v);
    u16 lo = f2bf(v - bf2f(h));
    u16* dst = Wcat + (size_t)l * 128 * 256 + (size_t)r * 256 + c;
    dst[0]   = h;
    dst[128] = lo;
}

// ---------- fused layer: X_out = act( A_hat * X_in @ W^T + b ) ----------
// Block = 64 target nodes, 512 threads (8 waves).
// Phase 1: each wave aggregates 8 nodes (gather on packed X_in) -> LDS tile
//          [64][256] u16, planar hi|lo, XOR-swizzled (byte ^= (row&7)<<4).
// Phase 2: MFMA GEMM (K=256 hi|lo trick) from LDS x W-slab -> write X_out.
template <int Dout, int OUT_MODE>
__global__ __launch_bounds__(512)
void k_layer(const u32* __restrict__ Xin, const u16* __restrict__ Wc,
             const float* __restrict__ b, const float* __restrict__ dinv,
             const int* __restrict__ fill, const int* __restrict__ slots,
             const float* __restrict__ wbuf, void* __restrict__ out, int N) {
    __shared__ u16 Asub[64 * 256];   // 32 KB, row stride 512 B
    const int tid = threadIdx.x;
    const int wave = tid >> 6, lane = tid & 63;
    const int node_base = blockIdx.x * 64;

    // ---- phase 1 ----
    for (int t = 0; t < 8; ++t) {
        const int lrow = wave * 8 + t;
        const int node = node_base + lrow;
        float Ax = 0.f, Ay = 0.f;
        const int d0 = lane * 2;
        if (node < N) {
            const int deg = min(fill[node], SLOTCAP);
            const float dc = dinv[node];
            int s_l = 0; float w_l = 0.f;
            if (lane < deg) {
                s_l = slots[node * SLOTCAP + lane];
                w_l = wbuf[node * SLOTCAP + lane];
            }
            float a0[8] = {}, a1[8] = {};
            {   // self term
                const uint2 sv = *(const uint2*)(Xin + (size_t)node * 128 + d0);
                a0[0] = dc * unpackhl(sv.x);
                a1[0] = dc * unpackhl(sv.y);
            }
            const int m8 = (deg + 7) & ~7;
            for (int j = 0; j < m8; j += 8) {
                int s[8]; float w[8];
                #pragma unroll
                for (int q = 0; q < 8; ++q) {
                    s[q] = __shfl(s_l, j + q);
                    w[q] = __shfl(w_l, j + q);
                }
                uint2 h[8];
                #pragma unroll
                for (int q = 0; q < 8; ++q)
                    h[q] = *(const uint2*)(Xin + (size_t)s[q] * 128 + d0);
                #pragma unroll
                for (int q = 0; q < 8; ++q) {
                    a0[q] = fmaf(w[q], unpackhl(h[q].x), a0[q]);
                    a1[q] = fmaf(w[q], unpackhl(h[q].y), a1[q]);
                }
            }
            float A0 = ((a0[0] + a0[1]) + (a0[2] + a0[3])) + ((a0[4] + a0[5]) + (a0[6] + a0[7]));
            float A1 = ((a1[0] + a1[1]) + (a1[2] + a1[3])) + ((a1[4] + a1[5]) + (a1[6] + a1[7]));
            Ax = dc * A0; Ay = dc * A1;
        }
        // split + LDS write (planar hi|lo, swizzled)
        const u16 h0 = f2bf(Ax), h1 = f2bf(Ay);
        const u16 l0 = f2bf(Ax - bf2f(h0)), l1 = f2bf(Ay - bf2f(h1));
        const u32 C = (u32)((lrow & 7) << 4);
        char* base = (char*)Asub + lrow * 512;
        *(u32*)(base + ((4 * lane) ^ C))       = (u32)h0 | ((u32)h1 << 16);
        *(u32*)(base + ((256 + 4 * lane) ^ C)) = (u32)l0 | ((u32)l1 << 16);
    }
    __syncthreads();

    // ---- phase 2: GEMM from LDS ----
    constexpr int FM = (Dout == 128) ? 2 : 1;
    constexpr int FN = 2;
    const int wm = (Dout == 128) ? (wave >> 2) : (wave >> 1);
    const int wn = (Dout == 128) ? (wave & 3) : (wave & 1);
    const int rbase = wm * (FM * 16);
    const int cbase = wn * (FN * 16);
    const int lr = lane & 15, kg = lane >> 4;

    f32x4 acc[FM][FN] = {};
    #pragma unroll
    for (int ks = 0; ks < 8; ++ks) {
        bf16x8 a[FM], bw[FN];
        #pragma unroll
        for (int i = 0; i < FM; ++i) {
            const int row = rbase + i * 16 + lr;
            const int byte = row * 512 + ((ks * 64 + kg * 16) ^ ((row & 7) << 4));
            a[i] = *(const bf16x8*)((const char*)Asub + byte);
        }
        #pragma unroll
        for (int j = 0; j < FN; ++j)
            bw[j] = *(const bf16x8*)(Wc + (size_t)(cbase + j * 16 + lr) * 256 + ks * 32 + kg * 8);
        #pragma unroll
        for (int i = 0; i < FM; ++i)
            #pragma unroll
            for (int j = 0; j < FN; ++j)
                acc[i][j] = __builtin_amdgcn_mfma_f32_16x16x32_bf16(a[i], bw[j], acc[i][j], 0, 0, 0);
    }

    // ---- epilogue ----
    #pragma unroll
    for (int i = 0; i < FM; ++i) {
        #pragma unroll
        for (int j = 0; j < FN; ++j) {
            #pragma unroll
            for (int q = 0; q < 4; ++q) {
                const int lrow = rbase + i * 16 + kg * 4 + q;
                const int node = node_base + lrow;
                if (node >= N) continue;
                const int col = cbase + j * 16 + lr;
                float v = acc[i][j][q] + b[col];
                if (OUT_MODE == 1) {
                    v = fmaxf(v, 0.0f);
                    ((u32*)out)[(size_t)node * 128 + col] = packhl(v);
                } else {
                    ((float*)out)[(size_t)node * Dout + col] = v;
                }
            }
        }
    }
}

extern "C" void kernel_launch(void* const* d_in, const int* in_sizes, int n_in,
                              void* d_out, int out_size, void* d_ws, size_t ws_size,
                              hipStream_t stream) {
    const float* x  = (const float*)d_in[0];
    const int*   ei = (const int*)d_in[1];
    const float* W[4] = {(const float*)d_in[2], (const float*)d_in[4],
                         (const float*)d_in[6], (const float*)d_in[8]};
    const float* B[4] = {(const float*)d_in[3], (const float*)d_in[5],
                         (const float*)d_in[7], (const float*)d_in[9]};
    const int N = in_sizes[0] / 128;
    const int E = in_sizes[1] / 2;
    const int Mpad = (N + 127) & ~127;
    const int* rowv = ei;        // sources
    const int* colv = ei + E;    // targets

    // workspace carve-up
    size_t nPad = ((size_t)N + 255) & ~(size_t)255;
    int*   fill  = (int*)d_ws;                             // [N]
    float* dinv  = (float*)(fill + nPad);                  // [N]
    int*   slots = (int*)(dinv + nPad);                    // [N*64]
    float* wbuf  = (float*)(slots + (size_t)N * SLOTCAP);  // [N*64]
    u32*   XA    = (u32*)(wbuf + (size_t)N * SLOTCAP);     // [Mpad][128] u32 (hi|lo)
    u32*   XB    = XA + (size_t)Mpad * 128;                // [Mpad][128] u32
    u16*   Wcat  = (u16*)(XB + (size_t)Mpad * 128);        // 4 x [128][256] bf16

    const int TB = 256;
    int nbE = (E + TB - 1) / TB;

    // --- prep ---
    hipMemsetAsync(fill, 0, (size_t)N * sizeof(int), stream);
    k_fill<<<nbE, TB, 0, stream>>>(rowv, colv, fill, slots, E);
    k_split_x<<<(Mpad * 32 + TB - 1) / TB, TB, 0, stream>>>(x, XA, fill, dinv, N, Mpad);
    k_wfill<<<(N * SLOTCAP + TB - 1) / TB, TB, 0, stream>>>(fill, slots, dinv, wbuf, N);
    {
        dim3 g(64, 4);
        k_split_w<<<g, TB, 0, stream>>>(W[0], W[1], W[2], W[3], Wcat);
    }

    const int lgrid = (N + 63) / 64;
    const size_t wsl = (size_t)128 * 256;

    k_layer<128, 1><<<lgrid, 512, 0, stream>>>(XA, Wcat + 0 * wsl, B[0], dinv, fill,
                                               slots, wbuf, (void*)XB, N);
    k_layer<128, 1><<<lgrid, 512, 0, stream>>>(XB, Wcat + 1 * wsl, B[1], dinv, fill,
                                               slots, wbuf, (void*)XA, N);
    k_layer<128, 1><<<lgrid, 512, 0, stream>>>(XA, Wcat + 2 * wsl, B[2], dinv, fill,
                                               slots, wbuf, (void*)XB, N);
    k_layer<64, 0><<<lgrid, 512, 0, stream>>>(XB, Wcat + 3 * wsl, B[3], dinv, fill,
                                              slots, wbuf, d_out, N);
}

// Round 11
// 310.670 us; speedup vs baseline: 1.1939x; 1.1939x over previous
//
#include <hip/hip_runtime.h>

#define D_INF 128
#define SLOTCAP 64

typedef __attribute__((ext_vector_type(8))) short bf16x8;
typedef __attribute__((ext_vector_type(4))) float f32x4;
typedef unsigned short u16;
typedef unsigned int   u32;

__device__ inline u16 f2bf(float f) {
    u32 u = __float_as_uint(f);
    u32 r = (u + 0x7fffu + ((u >> 16) & 1u)) >> 16;   // RNE
    return (u16)r;
}
__device__ inline float bf2f(u16 h) { return __uint_as_float(((u32)h) << 16); }

// ---------- adjacency build: bucket edges by target ----------
__global__ void k_fill(const int* __restrict__ rowv, const int* __restrict__ colv,
                       int* __restrict__ fill, int* __restrict__ slots, int E) {
    int e = blockIdx.x * blockDim.x + threadIdx.x;
    if (e >= E) return;
    int c = colv[e];
    int pos = atomicAdd(&fill[c], 1);
    if (pos < SLOTCAP) slots[c * SLOTCAP + pos] = rowv[e];
}

// ---------- per-slot weights: wbuf[c*64+i] = dinv[slots[c*64+i]] ----------
__global__ void k_wfill(const int* __restrict__ fill, const int* __restrict__ slots,
                        const float* __restrict__ dinv, float* __restrict__ wbuf, int N) {
    int i = blockIdx.x * 256 + threadIdx.x;
    if (i >= N * SLOTCAP) return;
    const int node = i >> 6, sl = i & 63;
    const int deg = min(fill[node], SLOTCAP);
    wbuf[i] = (sl < deg) ? dinv[slots[i]] : 0.0f;
}

// ---------- f32 -> bf16 hi|lo split (+ dinv from fill) ----------
__global__ void k_split_x(const float* __restrict__ x, u16* __restrict__ Xcat,
                          const int* __restrict__ fill, float* __restrict__ dinv,
                          int Nreal, int Mpad) {
    int idx = blockIdx.x * 256 + threadIdx.x;      // one thread per 4 elements
    int total = Mpad * 32;
    if (idx >= total) return;
    const int row = idx >> 5, c4 = (idx & 31) * 4;
    if (c4 == 0 && row < Nreal)
        dinv[row] = (float)(1.0 / sqrt((double)(fill[row] + 1)));   // +1 self-loop
    float4 v = make_float4(0.f, 0.f, 0.f, 0.f);
    if (row < Nreal) v = *(const float4*)(x + (size_t)row * 128 + c4);
    u16 h0 = f2bf(v.x), h1 = f2bf(v.y), h2 = f2bf(v.z), h3 = f2bf(v.w);
    u16 l0 = f2bf(v.x - bf2f(h0)), l1 = f2bf(v.y - bf2f(h1));
    u16 l2 = f2bf(v.z - bf2f(h2)), l3 = f2bf(v.w - bf2f(h3));
    u16* dst = Xcat + (size_t)row * 256 + c4;
    *(u32*)(dst)       = (u32)h0 | ((u32)h1 << 16);
    *(u32*)(dst + 2)   = (u32)h2 | ((u32)h3 << 16);
    *(u32*)(dst + 128) = (u32)l0 | ((u32)l1 << 16);
    *(u32*)(dst + 130) = (u32)l2 | ((u32)l3 << 16);
}

__global__ void k_split_w(const float* __restrict__ W0, const float* __restrict__ W1,
                          const float* __restrict__ W2, const float* __restrict__ W3,
                          u16* __restrict__ Wcat) {
    const int l = blockIdx.y;
    const float* W = (l == 0) ? W0 : (l == 1) ? W1 : (l == 2) ? W2 : W3;
    const int rows = (l == 3) ? 64 : 128;
    int idx = blockIdx.x * 256 + threadIdx.x;
    if (idx >= rows * 128) return;
    const int r = idx >> 7, c = idx & 127;
    float v = W[idx];
    u16 h = f2bf(v);
    u16 lo = f2bf(v - bf2f(h));
    u16* dst = Wcat + (size_t)l * 128 * 256 + (size_t)r * 256 + c;
    dst[0]   = h;
    dst[128] = lo;
}

// ---------- MFMA GEMM: H[Mpad,Dout] = Xcat[Mpad,256] @ Wcat[Dout,256]^T ----------
// Block = 128 rows, 4 waves; each wave owns 32 rows x FULL Dout (FM=2, FN=Dout/16)
// so every Xcat row is fetched exactly once per layer. W slab is L2-resident.
template <int Dout>
__global__ __launch_bounds__(256)
void k_gemm_mfma(const u16* __restrict__ Xcat, const u16* __restrict__ Wcat,
                 float* __restrict__ H) {
    constexpr int FN = Dout / 16;
    const int tid = threadIdx.x;
    const int wave = tid >> 6, lane = tid & 63;
    const int rbase = blockIdx.x * 128 + wave * 32;
    const int lr = lane & 15;
    const int kg = lane >> 4;       // k-group (0..3)

    f32x4 acc[2][FN] = {};

    #pragma unroll 2
    for (int ks = 0; ks < 8; ++ks) {
        const int k0 = ks * 32 + kg * 8;
        bf16x8 a[2], bw[FN];
        #pragma unroll
        for (int i = 0; i < 2; ++i)
            a[i] = *(const bf16x8*)(Xcat + (size_t)(rbase + i * 16 + lr) * 256 + k0);
        #pragma unroll
        for (int j = 0; j < FN; ++j)
            bw[j] = *(const bf16x8*)(Wcat + (size_t)(j * 16 + lr) * 256 + k0);
        #pragma unroll
        for (int i = 0; i < 2; ++i)
            #pragma unroll
            for (int j = 0; j < FN; ++j)
                acc[i][j] = __builtin_amdgcn_mfma_f32_16x16x32_bf16(a[i], bw[j], acc[i][j], 0, 0, 0);
    }

    #pragma unroll
    for (int i = 0; i < 2; ++i) {
        const int r0 = rbase + i * 16 + kg * 4;
        #pragma unroll
        for (int j = 0; j < FN; ++j) {
            const int c = j * 16 + lr;
            #pragma unroll
            for (int q = 0; q < 4; ++q)
                H[(size_t)(r0 + q) * Dout + c] = acc[i][j][q];
        }
    }
}

// ---------- gather-aggregate + bias (+relu), slot-bucket adjacency ----------
// One wave per node; <=64 edges in one slot segment. (src,w) loaded coalesced
// in PARALLEL (w precomputed), shfl-broadcast; 8 gathers in flight; f32 accum.
// out[c] = dinv[c] * ( dinv[c]*h[c] + sum_e w_e*h[src_e] ) + b
template <int D, int OUT_MODE>
__global__ void k_agg_gather(const float* __restrict__ H, const float* __restrict__ dinv,
                             const int* __restrict__ fill, const int* __restrict__ slots,
                             const float* __restrict__ wbuf, const float* __restrict__ b,
                             void* __restrict__ out, int N) {
    const int node = blockIdx.x * 4 + (threadIdx.x >> 6);
    const int lane = threadIdx.x & 63;
    if (node >= N) return;
    const int deg = min(fill[node], SLOTCAP);
    const float dc = dinv[node];

    int s_l = 0; float w_l = 0.f;
    if (lane < deg) {
        s_l = slots[node * SLOTCAP + lane];
        w_l = wbuf[node * SLOTCAP + lane];
    }
    const int m8 = (deg + 7) & ~7;

    if (D == 128) {
        const int d0 = lane * 2;
        float a0[8] = {}, a1[8] = {};
        {
            const float2 hs = *(const float2*)(H + (size_t)node * D + d0);
            a0[0] = dc * hs.x; a1[0] = dc * hs.y;   // self (x dc again at end)
        }
        for (int j = 0; j < m8; j += 8) {
            int s[8]; float w[8];
            #pragma unroll
            for (int q = 0; q < 8; ++q) {
                s[q] = __shfl(s_l, j + q);
                w[q] = __shfl(w_l, j + q);
            }
            float2 h[8];
            #pragma unroll
            for (int q = 0; q < 8; ++q)
                h[q] = *(const float2*)(H + (size_t)s[q] * D + d0);
            #pragma unroll
            for (int q = 0; q < 8; ++q) {
                a0[q] = fmaf(w[q], h[q].x, a0[q]);
                a1[q] = fmaf(w[q], h[q].y, a1[q]);
            }
        }
        float A0 = ((a0[0] + a0[1]) + (a0[2] + a0[3])) + ((a0[4] + a0[5]) + (a0[6] + a0[7]));
        float A1 = ((a1[0] + a1[1]) + (a1[2] + a1[3])) + ((a1[4] + a1[5]) + (a1[6] + a1[7]));
        float v0 = fmaf(dc, A0, b[d0]);
        float v1 = fmaf(dc, A1, b[d0 + 1]);
        if (OUT_MODE == 1) {
            v0 = fmaxf(v0, 0.0f); v1 = fmaxf(v1, 0.0f);
            const u16 h0 = f2bf(v0), h1 = f2bf(v1);
            const u16 l0 = f2bf(v0 - bf2f(h0)), l1 = f2bf(v1 - bf2f(h1));
            u16* xc = (u16*)out + (size_t)node * 256 + d0;
            *(u32*)(xc)       = (u32)h0 | ((u32)h1 << 16);
            *(u32*)(xc + 128) = (u32)l0 | ((u32)l1 << 16);
        } else {
            *(float2*)((float*)out + (size_t)node * D + d0) = make_float2(v0, v1);
        }
    } else {  // D == 64: two 32-lane halves; each half owns 4 of every 8 edges
        const int half = lane >> 5;
        const int l32 = lane & 31;
        const int d0 = l32 * 2;
        float a0[4] = {}, a1[4] = {};
        if (half == 0) {
            const float2 hs = *(const float2*)(H + (size_t)node * D + d0);
            a0[0] = dc * hs.x; a1[0] = dc * hs.y;
        }
        for (int j = 0; j < m8; j += 8) {
            int s[4]; float w[4];
            #pragma unroll
            for (int q = 0; q < 4; ++q) {
                const int e = j + 2 * q + half;
                s[q] = __shfl(s_l, e);
                w[q] = __shfl(w_l, e);
            }
            float2 h[4];
            #pragma unroll
            for (int q = 0; q < 4; ++q)
                h[q] = *(const float2*)(H + (size_t)s[q] * D + d0);
            #pragma unroll
            for (int q = 0; q < 4; ++q) {
                a0[q] = fmaf(w[q], h[q].x, a0[q]);
                a1[q] = fmaf(w[q], h[q].y, a1[q]);
            }
        }
        float A0 = (a0[0] + a0[1]) + (a0[2] + a0[3]);
        float A1 = (a1[0] + a1[1]) + (a1[2] + a1[3]);
        A0 += __shfl_xor(A0, 32);
        A1 += __shfl_xor(A1, 32);
        if (half == 0) {
            float v0 = fmaf(dc, A0, b[d0]);
            float v1 = fmaf(dc, A1, b[d0 + 1]);
            *(float2*)((float*)out + (size_t)node * D + d0) = make_float2(v0, v1);
        }
    }
}

extern "C" void kernel_launch(void* const* d_in, const int* in_sizes, int n_in,
                              void* d_out, int out_size, void* d_ws, size_t ws_size,
                              hipStream_t stream) {
    const float* x  = (const float*)d_in[0];
    const int*   ei = (const int*)d_in[1];
    const float* W[4] = {(const float*)d_in[2], (const float*)d_in[4],
                         (const float*)d_in[6], (const float*)d_in[8]};
    const float* B[4] = {(const float*)d_in[3], (const float*)d_in[5],
                         (const float*)d_in[7], (const float*)d_in[9]};
    const int N = in_sizes[0] / D_INF;
    const int E = in_sizes[1] / 2;
    const int Mpad = (N + 127) & ~127;
    const int* rowv = ei;        // sources
    const int* colv = ei + E;    // targets

    // workspace carve-up
    size_t nPad = ((size_t)N + 255) & ~(size_t)255;
    int*   fill  = (int*)d_ws;                             // [N]
    float* dinv  = (float*)(fill + nPad);                  // [N]
    int*   slots = (int*)(dinv + nPad);                    // [N*64]
    float* wbuf  = (float*)(slots + (size_t)N * SLOTCAP);  // [N*64]
    float* Hbuf  = wbuf + (size_t)N * SLOTCAP;             // [Mpad][128] f32
    u16*   Xcat  = (u16*)(Hbuf + (size_t)Mpad * 128);      // [Mpad][256] bf16
    u16*   Wcat  = Xcat + (size_t)Mpad * 256;              // 4 x [128][256] bf16

    const int TB = 256;
    int nbE = (E + TB - 1) / TB;

    // --- adjacency + dinv + weights + splits ---
    hipMemsetAsync(fill, 0, (size_t)N * sizeof(int), stream);
    k_fill<<<nbE, TB, 0, stream>>>(rowv, colv, fill, slots, E);
    k_split_x<<<(Mpad * 32 + TB - 1) / TB, TB, 0, stream>>>(x, Xcat, fill, dinv, N, Mpad);
    k_wfill<<<(N * SLOTCAP + TB - 1) / TB, TB, 0, stream>>>(fill, slots, dinv, wbuf, N);
    {
        dim3 g(64, 4);
        k_split_w<<<g, TB, 0, stream>>>(W[0], W[1], W[2], W[3], Wcat);
    }

    const int aggGrid = (N + 3) / 4;
    const int gemmGrid = Mpad / 128;

    // layers 0..2 : GEMM(128) -> gather -> Xcat(bf16 split)
    for (int l = 0; l < 3; ++l) {
        k_gemm_mfma<128><<<gemmGrid, 256, 0, stream>>>(Xcat, Wcat + (size_t)l * 128 * 256, Hbuf);
        k_agg_gather<128, 1><<<aggGrid, TB, 0, stream>>>(Hbuf, dinv, fill, slots, wbuf,
                                                         B[l], (void*)Xcat, N);
    }
    // layer 3 : GEMM(64) -> gather -> d_out (f32)
    k_gemm_mfma<64><<<gemmGrid, 256, 0, stream>>>(Xcat, Wcat + (size_t)3 * 128 * 256, Hbuf);
    k_agg_gather<64, 0><<<aggGrid, TB, 0, stream>>>(Hbuf, dinv, fill, slots, wbuf,
                                                    B[3], d_out, N);
}

// Round 12
// 298.879 us; speedup vs baseline: 1.2410x; 1.0394x over previous
//
#include <hip/hip_runtime.h>

#define D_INF 128
#define SLOTCAP 64

typedef __attribute__((ext_vector_type(8))) short bf16x8;
typedef __attribute__((ext_vector_type(4))) float f32x4;
typedef unsigned short u16;
typedef unsigned int   u32;

__device__ inline u16 f2bf(float f) {
    u32 u = __float_as_uint(f);
    u32 r = (u + 0x7fffu + ((u >> 16) & 1u)) >> 16;   // RNE
    return (u16)r;
}
__device__ inline float bf2f(u16 h) { return __uint_as_float(((u32)h) << 16); }

// ---------- adjacency build: bucket edges by target ----------
__global__ void k_fill(const int* __restrict__ rowv, const int* __restrict__ colv,
                       int* __restrict__ fill, int* __restrict__ slots, int E) {
    int e = blockIdx.x * blockDim.x + threadIdx.x;
    if (e >= E) return;
    int c = colv[e];
    int pos = atomicAdd(&fill[c], 1);
    if (pos < SLOTCAP) slots[c * SLOTCAP + pos] = rowv[e];
}

// ---------- per-slot weights: wbuf[c*64+i] = dinv[slots[c*64+i]] ----------
__global__ void k_wfill(const int* __restrict__ fill, const int* __restrict__ slots,
                        const float* __restrict__ dinv, float* __restrict__ wbuf, int N) {
    int i = blockIdx.x * 256 + threadIdx.x;
    if (i >= N * SLOTCAP) return;
    const int node = i >> 6, sl = i & 63;
    const int deg = min(fill[node], SLOTCAP);
    wbuf[i] = (sl < deg) ? dinv[slots[i]] : 0.0f;
}

// ---------- f32 -> bf16 hi|lo split (+ dinv from fill) ----------
__global__ void k_split_x(const float* __restrict__ x, u16* __restrict__ Xcat,
                          const int* __restrict__ fill, float* __restrict__ dinv,
                          int Nreal, int Mpad) {
    int idx = blockIdx.x * 256 + threadIdx.x;      // one thread per 4 elements
    int total = Mpad * 32;
    if (idx >= total) return;
    const int row = idx >> 5, c4 = (idx & 31) * 4;
    if (c4 == 0 && row < Nreal)
        dinv[row] = (float)(1.0 / sqrt((double)(fill[row] + 1)));   // +1 self-loop
    float4 v = make_float4(0.f, 0.f, 0.f, 0.f);
    if (row < Nreal) v = *(const float4*)(x + (size_t)row * 128 + c4);
    u16 h0 = f2bf(v.x), h1 = f2bf(v.y), h2 = f2bf(v.z), h3 = f2bf(v.w);
    u16 l0 = f2bf(v.x - bf2f(h0)), l1 = f2bf(v.y - bf2f(h1));
    u16 l2 = f2bf(v.z - bf2f(h2)), l3 = f2bf(v.w - bf2f(h3));
    u16* dst = Xcat + (size_t)row * 256 + c4;
    *(u32*)(dst)       = (u32)h0 | ((u32)h1 << 16);
    *(u32*)(dst + 2)   = (u32)h2 | ((u32)h3 << 16);
    *(u32*)(dst + 128) = (u32)l0 | ((u32)l1 << 16);
    *(u32*)(dst + 130) = (u32)l2 | ((u32)l3 << 16);
}

__global__ void k_split_w(const float* __restrict__ W0, const float* __restrict__ W1,
                          const float* __restrict__ W2, const float* __restrict__ W3,
                          u16* __restrict__ Wcat) {
    const int l = blockIdx.y;
    const float* W = (l == 0) ? W0 : (l == 1) ? W1 : (l == 2) ? W2 : W3;
    const int rows = (l == 3) ? 64 : 128;
    int idx = blockIdx.x * 256 + threadIdx.x;
    if (idx >= rows * 128) return;
    const int r = idx >> 7, c = idx & 127;
    float v = W[idx];
    u16 h = f2bf(v);
    u16 lo = f2bf(v - bf2f(h));
    u16* dst = Wcat + (size_t)l * 128 * 256 + (size_t)r * 256 + c;
    dst[0]   = h;
    dst[128] = lo;
}

// ---------- MFMA GEMM: H[Mpad,Dout] = Xcat[Mpad,256] @ Wcat[Dout,256]^T ----------
// BM=128, 4 waves. FM=4: Dout=128, waves 2x2 (wave tile 64x64).
//                  FM=2: Dout=64,  waves 4x1 (wave tile 32x64).
template <int FM>
__global__ __launch_bounds__(256)
void k_gemm_mfma(const u16* __restrict__ Xcat, const u16* __restrict__ Wcat,
                 float* __restrict__ H) {
    constexpr int Dout = (FM == 4) ? 128 : 64;
    const int tid = threadIdx.x;
    const int wave = tid >> 6, lane = tid & 63;
    const int wm = (FM == 4) ? (wave >> 1) : wave;
    const int wn = (FM == 4) ? (wave & 1) : 0;
    const int row_base = blockIdx.x * 128 + wm * (FM * 16);
    const int col_base = wn * 64;
    const int lr = lane & 15;
    const int kg = lane >> 4;       // k-group (0..3)

    f32x4 acc[FM][4] = {};

    #pragma unroll 2
    for (int ks = 0; ks < 8; ++ks) {
        const int k0 = ks * 32 + kg * 8;
        bf16x8 a[FM], b[4];
        #pragma unroll
        for (int i = 0; i < FM; ++i)
            a[i] = *(const bf16x8*)(Xcat + (size_t)(row_base + i * 16 + lr) * 256 + k0);
        #pragma unroll
        for (int j = 0; j < 4; ++j)
            b[j] = *(const bf16x8*)(Wcat + (size_t)(col_base + j * 16 + lr) * 256 + k0);
        #pragma unroll
        for (int i = 0; i < FM; ++i)
            #pragma unroll
            for (int j = 0; j < 4; ++j)
                acc[i][j] = __builtin_amdgcn_mfma_f32_16x16x32_bf16(a[i], b[j], acc[i][j], 0, 0, 0);
    }

    #pragma unroll
    for (int i = 0; i < FM; ++i) {
        const int r0 = row_base + i * 16 + kg * 4;
        #pragma unroll
        for (int j = 0; j < 4; ++j) {
            const int c = col_base + j * 16 + lr;
            #pragma unroll
            for (int q = 0; q < 4; ++q)
                H[(size_t)(r0 + q) * Dout + c] = acc[i][j][q];
        }
    }
}

// ---------- gather-aggregate + bias (+relu), slot-bucket adjacency ----------
// One wave per node; <=64 edges in one slot segment. (src,w) loaded coalesced
// in PARALLEL (w precomputed), shfl-broadcast; 8 gathers in flight; f32 accum.
// out[c] = dinv[c] * ( dinv[c]*h[c] + sum_e w_e*h[src_e] ) + b
template <int D, int OUT_MODE>
__global__ void k_agg_gather(const float* __restrict__ H, const float* __restrict__ dinv,
                             const int* __restrict__ fill, const int* __restrict__ slots,
                             const float* __restrict__ wbuf, const float* __restrict__ b,
                             void* __restrict__ out, int N) {
    const int node = blockIdx.x * 4 + (threadIdx.x >> 6);
    const int lane = threadIdx.x & 63;
    if (node >= N) return;
    const int deg = min(fill[node], SLOTCAP);
    const float dc = dinv[node];

    int s_l = 0; float w_l = 0.f;
    if (lane < deg) {
        s_l = slots[node * SLOTCAP + lane];
        w_l = wbuf[node * SLOTCAP + lane];
    }
    const int m8 = (deg + 7) & ~7;

    if (D == 128) {
        const int d0 = lane * 2;
        float a0[8] = {}, a1[8] = {};
        {
            const float2 hs = *(const float2*)(H + (size_t)node * D + d0);
            a0[0] = dc * hs.x; a1[0] = dc * hs.y;   // self (x dc again at end)
        }
        for (int j = 0; j < m8; j += 8) {
            int s[8]; float w[8];
            #pragma unroll
            for (int q = 0; q < 8; ++q) {
                s[q] = __shfl(s_l, j + q);
                w[q] = __shfl(w_l, j + q);
            }
            float2 h[8];
            #pragma unroll
            for (int q = 0; q < 8; ++q)
                h[q] = *(const float2*)(H + (size_t)s[q] * D + d0);
            #pragma unroll
            for (int q = 0; q < 8; ++q) {
                a0[q] = fmaf(w[q], h[q].x, a0[q]);
                a1[q] = fmaf(w[q], h[q].y, a1[q]);
            }
        }
        float A0 = ((a0[0] + a0[1]) + (a0[2] + a0[3])) + ((a0[4] + a0[5]) + (a0[6] + a0[7]));
        float A1 = ((a1[0] + a1[1]) + (a1[2] + a1[3])) + ((a1[4] + a1[5]) + (a1[6] + a1[7]));
        float v0 = fmaf(dc, A0, b[d0]);
        float v1 = fmaf(dc, A1, b[d0 + 1]);
        if (OUT_MODE == 1) {
            v0 = fmaxf(v0, 0.0f); v1 = fmaxf(v1, 0.0f);
            const u16 h0 = f2bf(v0), h1 = f2bf(v1);
            const u16 l0 = f2bf(v0 - bf2f(h0)), l1 = f2bf(v1 - bf2f(h1));
            u16* xc = (u16*)out + (size_t)node * 256 + d0;
            *(u32*)(xc)       = (u32)h0 | ((u32)h1 << 16);
            *(u32*)(xc + 128) = (u32)l0 | ((u32)l1 << 16);
        } else {
            *(float2*)((float*)out + (size_t)node * D + d0) = make_float2(v0, v1);
        }
    } else {  // D == 64: two 32-lane halves; each half owns 4 of every 8 edges
        const int half = lane >> 5;
        const int l32 = lane & 31;
        const int d0 = l32 * 2;
        float a0[4] = {}, a1[4] = {};
        if (half == 0) {
            const float2 hs = *(const float2*)(H + (size_t)node * D + d0);
            a0[0] = dc * hs.x; a1[0] = dc * hs.y;
        }
        for (int j = 0; j < m8; j += 8) {
            int s[4]; float w[4];
            #pragma unroll
            for (int q = 0; q < 4; ++q) {
                const int e = j + 2 * q + half;
                s[q] = __shfl(s_l, e);
                w[q] = __shfl(w_l, e);
            }
            float2 h[4];
            #pragma unroll
            for (int q = 0; q < 4; ++q)
                h[q] = *(const float2*)(H + (size_t)s[q] * D + d0);
            #pragma unroll
            for (int q = 0; q < 4; ++q) {
                a0[q] = fmaf(w[q], h[q].x, a0[q]);
                a1[q] = fmaf(w[q], h[q].y, a1[q]);
            }
        }
        float A0 = (a0[0] + a0[1]) + (a0[2] + a0[3]);
        float A1 = (a1[0] + a1[1]) + (a1[2] + a1[3]);
        A0 += __shfl_xor(A0, 32);
        A1 += __shfl_xor(A1, 32);
        if (half == 0) {
            float v0 = fmaf(dc, A0, b[d0]);
            float v1 = fmaf(dc, A1, b[d0 + 1]);
            *(float2*)((float*)out + (size_t)node * D + d0) = make_float2(v0, v1);
        }
    }
}

extern "C" void kernel_launch(void* const* d_in, const int* in_sizes, int n_in,
                              void* d_out, int out_size, void* d_ws, size_t ws_size,
                              hipStream_t stream) {
    const float* x  = (const float*)d_in[0];
    const int*   ei = (const int*)d_in[1];
    const float* W[4] = {(const float*)d_in[2], (const float*)d_in[4],
                         (const float*)d_in[6], (const float*)d_in[8]};
    const float* B[4] = {(const float*)d_in[3], (const float*)d_in[5],
                         (const float*)d_in[7], (const float*)d_in[9]};
    const int N = in_sizes[0] / D_INF;
    const int E = in_sizes[1] / 2;
    const int Mpad = (N + 127) & ~127;
    const int* rowv = ei;        // sources
    const int* colv = ei + E;    // targets

    // workspace carve-up
    size_t nPad = ((size_t)N + 255) & ~(size_t)255;
    int*   fill  = (int*)d_ws;                             // [N]
    float* dinv  = (float*)(fill + nPad);                  // [N]
    int*   slots = (int*)(dinv + nPad);                    // [N*64]
    float* wbuf  = (float*)(slots + (size_t)N * SLOTCAP);  // [N*64]
    float* Hbuf  = wbuf + (size_t)N * SLOTCAP;             // [Mpad][128] f32
    u16*   Xcat  = (u16*)(Hbuf + (size_t)Mpad * 128);      // [Mpad][256] bf16
    u16*   Wcat  = Xcat + (size_t)Mpad * 256;              // 4 x [128][256] bf16

    const int TB = 256;
    int nbE = (E + TB - 1) / TB;

    // --- adjacency + dinv + weights + splits ---
    hipMemsetAsync(fill, 0, (size_t)N * sizeof(int), stream);
    k_fill<<<nbE, TB, 0, stream>>>(rowv, colv, fill, slots, E);
    k_split_x<<<(Mpad * 32 + TB - 1) / TB, TB, 0, stream>>>(x, Xcat, fill, dinv, N, Mpad);
    k_wfill<<<(N * SLOTCAP + TB - 1) / TB, TB, 0, stream>>>(fill, slots, dinv, wbuf, N);
    {
        dim3 g(64, 4);
        k_split_w<<<g, TB, 0, stream>>>(W[0], W[1], W[2], W[3], Wcat);
    }

    const int aggGrid = (N + 3) / 4;
    const int gemmGrid = Mpad / 128;

    // layers 0..2 : GEMM(128) -> gather -> Xcat(bf16 split)
    for (int l = 0; l < 3; ++l) {
        k_gemm_mfma<4><<<gemmGrid, 256, 0, stream>>>(Xcat, Wcat + (size_t)l * 128 * 256, Hbuf);
        k_agg_gather<128, 1><<<aggGrid, TB, 0, stream>>>(Hbuf, dinv, fill, slots, wbuf,
                                                         B[l], (void*)Xcat, N);
    }
    // layer 3 : GEMM(64) -> gather -> d_out (f32)
    k_gemm_mfma<2><<<gemmGrid, 256, 0, stream>>>(Xcat, Wcat + (size_t)3 * 128 * 256, Hbuf);
    k_agg_gather<64, 0><<<aggGrid, TB, 0, stream>>>(Hbuf, dinv, fill, slots, wbuf,
                                                    B[3], d_out, N);
}